// Round 4
// baseline (121051.587 us; speedup 1.0000x reference)
//
#include <hip/hip_runtime.h>

#define T_   256
#define B_   64
#define H_   1024
#define Hh_  512
#define L_   2
#define MAXF 0.875f
#define NBLK 64
#define NT   1024

// ---- ws float offsets ----
#define OFF_WX   0u          // [2 l][16 blk][1024 k][192 c]   x-part weights
#define OFF_WH   6291456u    // per l (stride WH_L): P1 [16][512][64], P2 [16][512][32], P3, P4
#define OFF_XT   9437184u    // [2 buf][1024 k][64 r]
#define OFF_HT   9568256u    // [2 l][2 par][1024 n][64 r]
#define OFF_ZT   9830400u    // [2 l][512 n][64 r]
#define OFF_RHT  9895936u    // [2 l][512 n][64 r]
#define OFF_XC   9961472u    // [2 l][2 par][3072 cc][64 r]  cc: zr1|g1|zr2|g2
#define OFF_BARS 10747904u   // u32[512], counters strided 16 u32 (64B) apart

#define WH_L  1572864u
#define WH_P2 524288u
#define WH_P3 786432u
#define WH_P4 1310720u

// Chain weights: rows 1024..1535 of W[l], col-sliced 16 ways. [l][16 b][512 k][C c]
__global__ __launch_bounds__(256) void retile_wh(const float* __restrict__ src,
                                                 float* __restrict__ dst,
                                                 int N, int C, int Lstride) {
    size_t tid = (size_t)blockIdx.x * 256 + threadIdx.x;
    size_t total = (size_t)L_ * 512 * N;
    if (tid >= total) return;
    int c = (int)(tid % C);
    int k = (int)((tid / C) % 512);
    int b = (int)((tid / ((size_t)C * 512)) % 16);   // N/C == 16 for both shapes
    int l = (int)(tid / ((size_t)C * 512 * 16));
    dst[(size_t)l * Lstride + ((size_t)b * 512 + k) * C + c] =
        src[((size_t)l * 1536 + 1024 + k) * N + b * C + c];
}

// Helper weights: rows 0..1023, combined cols cc = [zr1(1024)|g1(512)|zr2(1024)|g2(512)],
// sliced 16 ways x 192. dst [l][16 b][1024 k][192 cm]
__global__ __launch_bounds__(256) void retile_wx(const float* __restrict__ Wzr1,
                                                 const float* __restrict__ Wg1,
                                                 const float* __restrict__ Wzr2,
                                                 const float* __restrict__ Wg2,
                                                 float* __restrict__ dst) {
    size_t tid = (size_t)blockIdx.x * 256 + threadIdx.x;
    if (tid >= (size_t)L_ * 16 * 1024 * 192) return;
    int cm = (int)(tid % 192);
    int k  = (int)((tid / 192) % 1024);
    int b  = (int)((tid / (192 * 1024)) % 16);
    int l  = (int)(tid / ((size_t)192 * 1024 * 16));
    int cc = b * 192 + cm;
    const float* src; int col, nc;
    if (cc < 1024)      { src = Wzr1; col = cc;        nc = 1024; }
    else if (cc < 1536) { src = Wg1;  col = cc - 1024; nc = 512;  }
    else if (cc < 2560) { src = Wzr2; col = cc - 1536; nc = 1024; }
    else                { src = Wg2;  col = cc - 2560; nc = 512;  }
    dst[tid] = src[((size_t)l * 1536 + k) * nc + col];
}

// Device-coherent (cross-XCD, MALL-direct) access — round-0 semantics.
__device__ __forceinline__ float ld_coh(const float* p) {
    return __hip_atomic_load(p, __ATOMIC_RELAXED, __HIP_MEMORY_SCOPE_AGENT);
}
__device__ __forceinline__ void st_coh(float* p, float v) {
    __hip_atomic_store(p, v, __ATOMIC_RELAXED, __HIP_MEMORY_SCOPE_AGENT);
}

// Tree barrier; counters strided 16 u32 to separate cache lines.
__device__ __forceinline__ void tbar(unsigned* base, int ncnt, int group,
                                     unsigned* round) {
    *round += 1;
    const unsigned need = 4u * *round;
    __syncthreads();
    if (threadIdx.x < 64) {
        if (threadIdx.x == 0)
            __hip_atomic_fetch_add(&base[group * 16], 1u, __ATOMIC_RELAXED,
                                   __HIP_MEMORY_SCOPE_AGENT);
        const int j = ((int)threadIdx.x & (ncnt - 1)) * 16;
        for (;;) {
            unsigned v = __hip_atomic_load(&base[j], __ATOMIC_RELAXED,
                                           __HIP_MEMORY_SCOPE_AGENT);
            if (__all(v >= need)) break;
            __builtin_amdgcn_s_sleep(1);
        }
    }
    __syncthreads();
}

// Chain GEMM: red[64 r][C] += A[512 k][64 r]^T @ Wt[512 k][C].
// 16-way K-split (32 rows/wave, ONE latency exposure), LDS-atomic reduce.
template<int C>
__device__ __forceinline__ void dep_gemm(const float* __restrict__ Ap,
                                         const float* __restrict__ Wt,
                                         float* __restrict__ red) {
    const int tid  = threadIdx.x;
    const int lane = tid & 63;
    const int w    = __builtin_amdgcn_readfirstlane(tid >> 6);  // 0..15
    const int k0   = w * 32;
    for (int i = tid; i < 64 * (C + 1); i += NT) red[i] = 0.f;
    float av[32];
#pragma unroll
    for (int j = 0; j < 32; ++j)
        av[j] = ld_coh(Ap + (size_t)(k0 + j) * 64 + lane);
    float acc[C];
#pragma unroll
    for (int c = 0; c < C; ++c) acc[c] = 0.f;
    __syncthreads();
#pragma unroll
    for (int j = 0; j < 32; ++j) {
        const float* wr = Wt + (size_t)(k0 + j) * C;
#pragma unroll
        for (int c = 0; c < C; ++c) acc[c] = fmaf(av[j], wr[c], acc[c]);
    }
#pragma unroll
    for (int c = 0; c < C; ++c) atomicAdd(&red[lane * (C + 1) + c], acc[c]);
    __syncthreads();
}

// Helper GEMM: Xc[192 cc][64 r] = A[1024 k][64 r]^T @ Ws[1024 k][192 c].
// Waves: cg = w>>2 (48 cols each), ks = w&3 (256 rows each, 8 batches of 32).
__device__ __forceinline__ void helper_gemm(const float* __restrict__ Ap,
                                            const float* __restrict__ Ws,
                                            float* __restrict__ red,
                                            float* __restrict__ XcOut) {
    const int tid  = threadIdx.x;
    const int lane = tid & 63;
    const int w    = __builtin_amdgcn_readfirstlane(tid >> 6);
    const int cg   = w >> 2, ks = w & 3;
    for (int i = tid; i < 4 * 64 * 49; i += NT) red[i] = 0.f;
    float acc[48];
#pragma unroll
    for (int c = 0; c < 48; ++c) acc[c] = 0.f;
    __syncthreads();
#pragma unroll 1
    for (int kb = 0; kb < 256; kb += 32) {
        float av[32];
#pragma unroll
        for (int j = 0; j < 32; ++j)
            av[j] = ld_coh(Ap + (size_t)(ks * 256 + kb + j) * 64 + lane);
#pragma unroll
        for (int j = 0; j < 32; ++j) {
            const float* wr = Ws + (size_t)(ks * 256 + kb + j) * 192 + cg * 48;
#pragma unroll
            for (int c = 0; c < 48; ++c) acc[c] = fmaf(av[j], wr[c], acc[c]);
        }
    }
#pragma unroll
    for (int c = 0; c < 48; ++c)
        atomicAdd(&red[((cg << 6) | lane) * 49 + c], acc[c]);
    __syncthreads();
#pragma unroll
    for (int q = 0; q < 12; ++q) {
        int idx = q * NT + tid;
        int ccl = idx >> 6, r = idx & 63;
        int cg2 = ccl / 48, c2 = ccl - cg2 * 48;
        st_coh(&XcOut[(size_t)ccl * 64 + r], red[((cg2 << 6) | r) * 49 + c2]);
    }
}

// Roles (64 blocks): 0..15 C0, 16..31 C1, 32..47 H0, 48..63 H1.
// Iter s: H0: Xc_L0(t=s); C0: t=s-1; H1: Xc_L1(t=s-2); C1: t=s-3.
// All handoffs parity-double-buffered, separated by the end-of-iter global bar.
__global__ __launch_bounds__(NT) void revgru_main(
    const int* __restrict__ seq, const float* __restrict__ h0,
    const float* __restrict__ emb,
    const float* __restrict__ bzr1, const float* __restrict__ bg1,
    const float* __restrict__ bzr2, const float* __restrict__ bg2,
    float* __restrict__ ws, float* __restrict__ out)
{
    const int bi = blockIdx.x, tid = threadIdx.x;
    const bool isChain = (bi < 32);
    const int l  = (bi >> 4) & 1;
    const int bl = bi & 15;
    __shared__ float red[4 * 64 * 49];
    unsigned rG = 0, rC = 0;

    float* xT  = ws + OFF_XT;
    float* hT  = ws + OFF_HT;
    float* zT  = ws + OFF_ZT;
    float* rhT = ws + OFF_RHT;
    unsigned* bars = (unsigned*)(ws + OFF_BARS);
    unsigned* barC = bars + (l ? 64 : 0);
    unsigned* barG = bars + 128;

    const float* WhP1 = ws + OFF_WH + (size_t)l * WH_L + (size_t)bl * 512 * 64;
    const float* WhP2 = ws + OFF_WH + (size_t)l * WH_L + WH_P2 + (size_t)bl * 512 * 32;
    const float* WhP3 = ws + OFF_WH + (size_t)l * WH_L + WH_P3 + (size_t)bl * 512 * 64;
    const float* WhP4 = ws + OFF_WH + (size_t)l * WH_L + WH_P4 + (size_t)bl * 512 * 32;
    const float* Wx   = ws + OFF_WX + ((size_t)l * 16 + bl) * 1024 * 192;

    // ---- init: h0 -> hT[l][par=1]; x(0) -> xT[0] ----
#pragma unroll
    for (int q = 0; q < 2; ++q) {
        int g = bi * 2048 + q * NT + tid;
        int ll = g >> 16, rem = g & 65535, r = rem >> 10, n = rem & 1023;
        st_coh(&hT[(((size_t)ll * 2 + 1) * H_ + n) * 64 + r], h0[g]);
    }
    {
        int gx = bi * NT + tid;               // 0..65535
        int k = gx >> 6, rr = gx & 63;
        st_coh(&xT[gx], emb[(size_t)seq[rr] * H_ + k]);
    }
    tbar(barG, 16, bi >> 2, &rG);

    for (int s = 0; s <= 258; ++s) {
        if (isChain) {
            const int t = s - 1 - 2 * l;
            const bool act = (t >= 0) && (t < T_);
            const int par = t & 1;
            float* hC = hT + ((size_t)l * 2 + (t & 1)) * (H_ * 64);
            float* hP = hT + ((size_t)l * 2 + ((t & 1) ^ 1)) * (H_ * 64);
            float* zl  = zT  + (size_t)l * Hh_ * 64;
            float* rhl = rhT + (size_t)l * Hh_ * 64;
            const float* Xcb = ws + OFF_XC + ((size_t)l * 2 + par) * (3072 * 64);

            // ---- P1: zr1 = Xc + h2_old @ Wzr1[1024:] ----
            if (act) {
                dep_gemm<64>(hP + Hh_ * 64, WhP1, red);
#pragma unroll
                for (int q = 0; q < 4; ++q) {
                    int idx = q * NT + tid;
                    int c = idx >> 6, r = idx & 63, n = bl * 64 + c;
                    float v = red[r * 65 + c] + ld_coh(&Xcb[(size_t)n * 64 + r])
                            + bzr1[l * H_ + n];
                    float sg = 1.f / (1.f + __expf(-v));
                    if (n < Hh_) st_coh(&zl[(size_t)n * 64 + r], sg * MAXF + (1.f - MAXF));
                    else st_coh(&rhl[(size_t)(n - Hh_) * 64 + r],
                                sg * ld_coh(&hP[(size_t)n * 64 + r]));
                }
            }
            tbar(barC, 4, bl >> 2, &rC);
            // ---- P2: g1; h1_new ----
            if (act) {
                dep_gemm<32>(rhl, WhP2, red);
#pragma unroll
                for (int q = 0; q < 2; ++q) {
                    int idx = q * NT + tid;
                    int c = idx >> 6, r = idx & 63, n = bl * 32 + c;
                    float g = tanhf(red[r * 33 + c]
                                    + ld_coh(&Xcb[(size_t)(1024 + n) * 64 + r])
                                    + bg1[l * Hh_ + n]);
                    float z   = ld_coh(&zl[(size_t)n * 64 + r]);
                    float h1o = ld_coh(&hP[(size_t)n * 64 + r]);
                    st_coh(&hC[(size_t)n * 64 + r], z * h1o + (1.f - z) * g);
                }
            }
            tbar(barC, 4, bl >> 2, &rC);
            // ---- P3: zr2 = Xc + h1_new @ Wzr2[1024:] ----
            if (act) {
                dep_gemm<64>(hC, WhP3, red);
#pragma unroll
                for (int q = 0; q < 4; ++q) {
                    int idx = q * NT + tid;
                    int c = idx >> 6, r = idx & 63, n = bl * 64 + c;
                    float v = red[r * 65 + c]
                            + ld_coh(&Xcb[(size_t)(1536 + n) * 64 + r])
                            + bzr2[l * H_ + n];
                    float sg = 1.f / (1.f + __expf(-v));
                    if (n < Hh_) st_coh(&zl[(size_t)n * 64 + r], sg * MAXF + (1.f - MAXF));
                    else st_coh(&rhl[(size_t)(n - Hh_) * 64 + r],
                                sg * ld_coh(&hC[(size_t)(n - Hh_) * 64 + r]));
                }
            }
            tbar(barC, 4, bl >> 2, &rC);
            // ---- P4: g2; h2_new ----
            if (act) {
                dep_gemm<32>(rhl, WhP4, red);
#pragma unroll
                for (int q = 0; q < 2; ++q) {
                    int idx = q * NT + tid;
                    int c = idx >> 6, r = idx & 63, n = bl * 32 + c;
                    float g = tanhf(red[r * 33 + c]
                                    + ld_coh(&Xcb[(size_t)(2560 + n) * 64 + r])
                                    + bg2[l * Hh_ + n]);
                    float z   = ld_coh(&zl[(size_t)n * 64 + r]);
                    float h2o = ld_coh(&hP[(size_t)(Hh_ + n) * 64 + r]);
                    st_coh(&hC[(size_t)(Hh_ + n) * 64 + r], z * h2o + (1.f - z) * g);
                }
            }
        } else {
            const int th = s - 2 * l;
            if (th >= 0 && th < T_) {
                const int par = th & 1;
                const float* Ap = (l == 0) ? (xT + (size_t)par * (H_ * 64))
                                           : (hT + (size_t)par * (H_ * 64));  // h_L0
                float* XcOut = ws + OFF_XC +
                    (((size_t)l * 2 + par) * 3072 + (size_t)bl * 192) * 64;
                helper_gemm(Ap, Wx, red, XcOut);
                if (l == 0 && th + 1 < T_) {   // gather x(th+1) into other buf
#pragma unroll
                    for (int q = 0; q < 4; ++q) {
                        int idx = bl * 4096 + q * NT + tid;   // 0..65535
                        int k = idx >> 6, rr = idx & 63;
                        st_coh(&xT[(size_t)((th + 1) & 1) * (H_ * 64) + idx],
                               emb[(size_t)seq[(th + 1) * B_ + rr] * H_ + k]);
                    }
                }
            }
        }
        tbar(barG, 16, bi >> 2, &rG);
    }
    // out[l][r][n] = hT[l][par=1][n][r]  (t=255 -> par 1 for both layers)
#pragma unroll
    for (int q = 0; q < 2; ++q) {
        int g = bi * 2048 + q * NT + tid;
        int ll = g >> 16, rem = g & 65535, r = rem >> 10, n = rem & 1023;
        out[g] = ld_coh(&hT[(((size_t)ll * 2 + 1) * H_ + n) * 64 + r]);
    }
}

extern "C" void kernel_launch(void* const* d_in, const int* in_sizes, int n_in,
                              void* d_out, int out_size, void* d_ws, size_t ws_size,
                              hipStream_t stream) {
    (void)in_sizes; (void)n_in; (void)out_size; (void)ws_size;
    const int*   seq  = (const int*)  d_in[0];
    const float* h0   = (const float*)d_in[1];
    const float* emb  = (const float*)d_in[2];
    const float* Wzr1 = (const float*)d_in[3];
    const float* bzr1 = (const float*)d_in[4];
    const float* Wg1  = (const float*)d_in[5];
    const float* bg1  = (const float*)d_in[6];
    const float* Wzr2 = (const float*)d_in[7];
    const float* bzr2 = (const float*)d_in[8];
    const float* Wg2  = (const float*)d_in[9];
    const float* bg2  = (const float*)d_in[10];
    float* out = (float*)d_out;
    float* ws  = (float*)d_ws;

    hipMemsetAsync((char*)d_ws + (size_t)OFF_BARS * 4, 0, 2048, stream);
    retile_wx<<<24576, 256, 0, stream>>>(Wzr1, Wg1, Wzr2, Wg2, ws + OFF_WX);
    retile_wh<<<4096, 256, 0, stream>>>(Wzr1, ws + OFF_WH, 1024, 64, WH_L);
    retile_wh<<<2048, 256, 0, stream>>>(Wg1,  ws + OFF_WH + WH_P2, 512, 32, WH_L);
    retile_wh<<<4096, 256, 0, stream>>>(Wzr2, ws + OFF_WH + WH_P3, 1024, 64, WH_L);
    retile_wh<<<2048, 256, 0, stream>>>(Wg2,  ws + OFF_WH + WH_P4, 512, 32, WH_L);

    void* args[] = { &seq, &h0, &emb, &bzr1, &bg1, &bzr2, &bg2, &ws, &out };
    hipLaunchCooperativeKernel((void*)revgru_main, dim3(NBLK), dim3(NT),
                               args, 0, stream);
}